// Round 10
// baseline (300.453 us; speedup 1.0000x reference)
//
#include <hip/hip_runtime.h>
#include <hip/hip_bf16.h>

// HyperPatchInvertedResidual: per-patch hyper-conv pipeline with global BNs.
// b=16, c=32, H=W=128, 8x8 patches of 16x16 (+1 halo -> 18x18), HID=192.
// G = 16*64 = 1024 groups.

#define HID 192
#define SP1 324   // 18*18
#define SP2 256   // 16*16
#define HPAR 14016
#define R1 6144   // 32*192
#define R2 7872   // R1 + 192*9
#define NGRP 1024
#define PSTR 36   // patch LDS row stride (halves): conflict-free frag reads

typedef __hip_bfloat16 bf16;
typedef __attribute__((ext_vector_type(4))) unsigned short ushort4v;
typedef __attribute__((ext_vector_type(2))) unsigned short ushort2v;  // 4B
typedef __attribute__((ext_vector_type(4))) short short4v;
typedef __attribute__((ext_vector_type(8))) short short8v;
typedef __attribute__((ext_vector_type(4))) float f32x4;
union Frag { short4v h[2]; short8v v; };

__device__ __forceinline__ float b2f(unsigned short u) {
  __hip_bfloat16_raw r; r.x = u;
  return __bfloat162float((bf16)r);
}
__device__ __forceinline__ unsigned short f2b(float f) {
  union { bf16 b; unsigned short u; } c;
  c.b = __float2bfloat16(f);
  return c.u;
}
// XCD-affinity remap: all 64 groups of one batch bi land on XCD bi%8.
__device__ __forceinline__ int remap_g(int blk) {
  int x = blk & 7, q = blk >> 3;
  return (((q >> 6) << 3) + x) * 64 + (q & 63);
}

// ---------------- K0: hyper-weight gather/transpose -------------------------
// s[bi][hp][8][8] f32 (stride-64 per-group gather) -> wt[g][hp] bf16, dense.
__global__ __launch_bounds__(256) void k0_wt(
    const float* __restrict__ s, unsigned short* __restrict__ wt) {
  int blk = blockIdx.x;             // 16 bi x 219 chunks of 64 hp
  int bi = blk / 219, ck = blk - bi * 219;
  int hp0 = ck * 64;
  __shared__ float t[64][65];
  int tid = threadIdx.x;
  int lw = tid >> 6, l = tid & 63;
  const float* sp = s + ((size_t)bi * HPAR + hp0) * 64;
#pragma unroll
  for (int i = 0; i < 16; ++i) {
    int row = lw * 16 + i;
    t[row][l] = sp[(size_t)row * 64 + l];
  }
  __syncthreads();
  int g = lw * 16 + (l >> 2), seg = l & 3;    // 64 g x 4 segs of 16 hp
  unsigned short* wp = wt + ((size_t)(bi * 64 + g)) * HPAR + hp0 + seg * 16;
#pragma unroll
  for (int q = 0; q < 4; ++q) {
    ushort4v ov;
    ov.x = f2b(t[seg * 16 + q * 4 + 0][g]);
    ov.y = f2b(t[seg * 16 + q * 4 + 1][g]);
    ov.z = f2b(t[seg * 16 + q * 4 + 2][g]);
    ov.w = f2b(t[seg * 16 + q * 4 + 3][g]);
    *(ushort4v*)(wp + q * 4) = ov;
  }
}

// ---------------- K1: stage1 1x1 conv 32->192 via MFMA + fused stats --------
// y1[192,324] = w1[192,32] @ patch[32,324] per group. Stats accumulated in
// registers (static idx inside unrolled loops), shuffles/atomics AFTER the
// compute loop only (round-2 lesson).
__global__ __launch_bounds__(256) void k1_stage1(
    const float* __restrict__ x, const unsigned short* __restrict__ wt,
    bf16* __restrict__ y1, float* __restrict__ sum1, float* __restrict__ sq1) {
  int g = remap_g(blockIdx.x);
  int bi = g >> 6, fi = (g >> 3) & 7, fj = g & 7;
  __shared__ unsigned short plds[336 * PSTR];    // [sp=336][ci], stride 36
  __shared__ float smS[192], smQ[192];
  int tid = threadIdx.x;
  int w = tid >> 6, l = tid & 63;
  int lj = l & 15, kg = l >> 4;
  const unsigned short* w1g = wt + (size_t)g * HPAR;
  Frag wf[12];
#pragma unroll
  for (int ot = 0; ot < 12; ++ot) {
    const unsigned short* wp = w1g + (ot * 16 + lj) * 32 + 4 * kg;
    wf[ot].h[0] = *(const short4v*)wp;
    wf[ot].h[1] = *(const short4v*)(wp + 16);
  }
  const float* xb = x + (size_t)bi * 32 * 128 * 128;
  for (int idx = tid; idx < 32 * SP1; idx += 256) {
    int ci = idx / SP1, sp = idx - ci * SP1;
    int a = sp / 18, b = sp - a * 18;
    int r = fi * 16 + a - 1; r = r < 0 ? -r : (r > 127 ? 254 - r : r);
    int c = fj * 16 + b - 1; c = c < 0 ? -c : (c > 127 ? 254 - c : c);
    plds[sp * PSTR + ci] = f2b(xb[((size_t)ci * 128 + r) * 128 + c]);
  }
  for (int i = tid; i < 12 * PSTR; i += 256) plds[SP1 * PSTR + i] = 0;  // pad rows
  if (tid < 192) { smS[tid] = 0.f; smQ[tid] = 0.f; }
  __syncthreads();

  float sreg[12], qreg[12];
#pragma unroll
  for (int ot = 0; ot < 12; ++ot) { sreg[ot] = 0.f; qreg[ot] = 0.f; }
  unsigned short* yg = (unsigned short*)y1 + (size_t)g * HID * SP1;
#pragma unroll 1
  for (int sti = 0; sti < 6; ++sti) {
    int st = sti * 4 + w;          // interleaved: balances the 21-tile tail
    int sp0 = st * 16;
    if (sp0 >= SP1) continue;      // tiles 21..23 are pure pad
    const unsigned short* pb = plds + (sp0 + lj) * PSTR + 4 * kg;
    Frag tf;
    tf.h[0] = *(const short4v*)pb;
    tf.h[1] = *(const short4v*)(pb + 16);
    int spb = sp0 + kg * 4;
    bool stok = spb + 3 < SP1;     // tile 20: only kg=0 (sp 320..323) valid
#pragma unroll
    for (int ot = 0; ot < 12; ++ot) {
      f32x4 zz = {0.f, 0.f, 0.f, 0.f};
      f32x4 d = __builtin_amdgcn_mfma_f32_16x16x32_bf16(tf.v, wf[ot].v, zz, 0, 0, 0);
      if (stok) {
        sreg[ot] += d[0] + d[1] + d[2] + d[3];
        qreg[ot] += d[0] * d[0] + d[1] * d[1] + d[2] * d[2] + d[3] * d[3];
        short4v ov;
        ov.x = (short)f2b(d[0]); ov.y = (short)f2b(d[1]);
        ov.z = (short)f2b(d[2]); ov.w = (short)f2b(d[3]);
        *(short4v*)(yg + (size_t)(ot * 16 + lj) * SP1 + spb) = ov;
      }
    }
  }
  // stats tail: kg-lane reduce, LDS combine, one global atomic per channel
#pragma unroll
  for (int ot = 0; ot < 12; ++ot) {
    float a = sreg[ot], b = qreg[ot];
    a += __shfl_down(a, 32); a += __shfl_down(a, 16);
    b += __shfl_down(b, 32); b += __shfl_down(b, 16);
    if (kg == 0) {
      atomicAdd(&smS[ot * 16 + lj], a);
      atomicAdd(&smQ[ot * 16 + lj], b);
    }
  }
  __syncthreads();
  if (tid < 192) {
    atomicAdd(&sum1[tid], smS[tid]);
    atomicAdd(&sq1[tid], smQ[tid]);
  }
}

// ---------------- bn params: scale/shift from sums --------------------------
__global__ void k_bnp(const float* __restrict__ sums, const float* __restrict__ sqs,
                      const float* __restrict__ gamma, const float* __restrict__ beta,
                      float* __restrict__ sc, float* __restrict__ sh,
                      int CH, float invN) {
  int ch = threadIdx.x;
  if (ch >= CH) return;
  float m = sums[ch] * invN;
  float v = sqs[ch] * invN - m * m;
  float scale = gamma[ch] * rsqrtf(v + 1e-5f);
  sc[ch] = scale;
  sh[ch] = beta[ch] - m * scale;
}

// ---------------- K3: bn1+relu6 then 3x3 depthwise + fused stats ------------
// LDS-free: thread-task = (channel, 4-col quad, all 16 out rows). Quad lanes
// are consecutive -> shfl(1/2) reduce, leader atomics. Still zero barriers.
__global__ __launch_bounds__(256) void k3_dw(
    const bf16* __restrict__ y1, const unsigned short* __restrict__ wt,
    const float* __restrict__ sc1, const float* __restrict__ sh1,
    bf16* __restrict__ y2, float* __restrict__ sum2, float* __restrict__ sq2) {
  int g = remap_g(blockIdx.x);
  const unsigned short* w2g = wt + (size_t)g * HPAR + R1;
  const unsigned short* y1g = (const unsigned short*)y1 + (size_t)g * HID * SP1;
  unsigned short* y2g = (unsigned short*)y2 + (size_t)g * HID * SP2;
  int tid = threadIdx.x;
#pragma unroll 1
  for (int p = 0; p < 3; ++p) {
    int tau = tid + 256 * p;            // 0..767
    int ch = tau >> 2, c4 = (tau & 3) * 4;
    float scv = sc1[ch], shv = sh1[ch];
    float wk[9];
#pragma unroll
    for (int k = 0; k < 9; ++k) wk[k] = b2f(w2g[ch * 9 + k]);
    const unsigned short* rp = y1g + ch * SP1 + c4;
    unsigned short* op = y2g + ch * SP2 + c4;
    float accR[3][4];
    float s0 = 0.f, s1 = 0.f;
#pragma unroll
    for (int ir = 0; ir < 18; ++ir) {
      ushort2v q0 = *(const ushort2v*)(rp + ir * 18);
      ushort2v q1 = *(const ushort2v*)(rp + ir * 18 + 2);
      ushort2v q2 = *(const ushort2v*)(rp + ir * 18 + 4);
      float w6[6];
      w6[0] = fminf(fmaxf(b2f(q0.x) * scv + shv, 0.f), 6.f);
      w6[1] = fminf(fmaxf(b2f(q0.y) * scv + shv, 0.f), 6.f);
      w6[2] = fminf(fmaxf(b2f(q1.x) * scv + shv, 0.f), 6.f);
      w6[3] = fminf(fmaxf(b2f(q1.y) * scv + shv, 0.f), 6.f);
      w6[4] = fminf(fmaxf(b2f(q2.x) * scv + shv, 0.f), 6.f);
      w6[5] = fminf(fmaxf(b2f(q2.y) * scv + shv, 0.f), 6.f);
#pragma unroll
      for (int k = 0; k < 3; ++k) {     // in row ir feeds out row ir-k (tap k)
        int orow = ir - k;
        if (orow < 0 || orow >= 16) continue;
        float* A = accR[orow % 3];      // static under full unroll
#pragma unroll
        for (int j = 0; j < 4; ++j) {
          float t = w6[j] * wk[3 * k] + w6[j + 1] * wk[3 * k + 1] +
                    w6[j + 2] * wk[3 * k + 2];
          A[j] = (k == 0) ? t : A[j] + t;
        }
        if (k == 2) {
          s0 += A[0] + A[1] + A[2] + A[3];
          s1 += A[0] * A[0] + A[1] * A[1] + A[2] * A[2] + A[3] * A[3];
          ushort4v ov;
          ov.x = f2b(A[0]); ov.y = f2b(A[1]);
          ov.z = f2b(A[2]); ov.w = f2b(A[3]);
          *(ushort4v*)(op + orow * 16) = ov;
        }
      }
    }
    // quad reduce (lanes 4q..4q+3 share ch), leader atomics
    s0 += __shfl_down(s0, 1); s0 += __shfl_down(s0, 2);
    s1 += __shfl_down(s1, 1); s1 += __shfl_down(s1, 2);
    if ((tid & 3) == 0) {
      atomicAdd(&sum2[ch], s0);
      atomicAdd(&sq2[ch], s1);
    }
  }
}

// ---------------- K5: bn2+relu6 then 1x1 conv 192->32 via MFMA + stats ------
__global__ __launch_bounds__(256) void k5_stage3(
    const bf16* __restrict__ y2, const unsigned short* __restrict__ wt,
    const float* __restrict__ sc2, const float* __restrict__ sh2,
    bf16* __restrict__ y3, float* __restrict__ sum3, float* __restrict__ sq3) {
  int g = remap_g(blockIdx.x);
  const unsigned short* w3g = wt + (size_t)g * HPAR + R2;   // [o2][k=192]
  __shared__ unsigned short bt[256 * PSTR];      // [sp=256][k-chunk=32], stride 36
  int tid = threadIdx.x;
  int w = tid >> 6, l = tid & 63;
  int lj = l & 15, kg = l >> 4;
  f32x4 acc[4][2] = {};
  const unsigned short* y2g = (const unsigned short*)y2 + (size_t)g * HID * SP2;
#pragma unroll 1
  for (int kc = 0; kc < 6; ++kc) {
    if (kc) __syncthreads();   // protect bt from previous chunk's readers
#pragma unroll
    for (int uu = 0; uu < 2; ++uu) {
      int u = tid + 256 * uu;
      int tq = u & 7, spq = u >> 3;           // k-quad, sp-quad
      int o0 = kc * 32 + tq * 4;
      float4 scv = *(const float4*)(sc2 + o0);
      float4 shv = *(const float4*)(sh2 + o0);
      unsigned short hbuf[4][4];
#pragma unroll
      for (int e = 0; e < 4; ++e) {
        ushort4v v = *(const ushort4v*)(y2g + (size_t)(o0 + e) * SP2 + spq * 4);
        float sce = ((const float*)&scv)[e], she = ((const float*)&shv)[e];
#pragma unroll
        for (int j = 0; j < 4; ++j) {
          float f = b2f(((const unsigned short*)&v)[j]) * sce + she;
          hbuf[e][j] = f2b(fminf(fmaxf(f, 0.f), 6.f));
        }
      }
#pragma unroll
      for (int j = 0; j < 4; ++j) {
        ushort4v wv;
        wv.x = hbuf[0][j]; wv.y = hbuf[1][j]; wv.z = hbuf[2][j]; wv.w = hbuf[3][j];
        *(ushort4v*)(bt + (spq * 4 + j) * PSTR + tq * 4) = wv;
      }
    }
    __syncthreads();
    Frag wf[2];
#pragma unroll
    for (int ot = 0; ot < 2; ++ot) {
      const unsigned short* wp = w3g + (ot * 16 + lj) * HID + kc * 32 + 4 * kg;
      wf[ot].h[0] = *(const short4v*)wp;
      wf[ot].h[1] = *(const short4v*)(wp + 16);
    }
#pragma unroll
    for (int sti = 0; sti < 4; ++sti) {
      const unsigned short* pb = bt + ((w + 4 * sti) * 16 + lj) * PSTR + 4 * kg;
      Frag tf;
      tf.h[0] = *(const short4v*)pb;
      tf.h[1] = *(const short4v*)(pb + 16);
#pragma unroll
      for (int ot = 0; ot < 2; ++ot)
        acc[sti][ot] = __builtin_amdgcn_mfma_f32_16x16x32_bf16(
            tf.v, wf[ot].v, acc[sti][ot], 0, 0, 0);
    }
  }
  // D[m=kg*4+r][n=lj]: m -> sp, n -> o2: direct short4 stores + stats.
  unsigned short* yg3 = (unsigned short*)y3 + (size_t)g * 32 * SP2;
  float ss[2] = {0.f, 0.f}, qq[2] = {0.f, 0.f};
#pragma unroll
  for (int sti = 0; sti < 4; ++sti) {
    int spb = (w + 4 * sti) * 16 + kg * 4;
#pragma unroll
    for (int ot = 0; ot < 2; ++ot) {
      int o2 = ot * 16 + lj;
      f32x4 d = acc[sti][ot];
      ss[ot] += d[0] + d[1] + d[2] + d[3];
      qq[ot] += d[0] * d[0] + d[1] * d[1] + d[2] * d[2] + d[3] * d[3];
      short4v ov;
      ov.x = (short)f2b(d[0]); ov.y = (short)f2b(d[1]);
      ov.z = (short)f2b(d[2]); ov.w = (short)f2b(d[3]);
      *(short4v*)(yg3 + (size_t)o2 * SP2 + spb) = ov;
    }
  }
#pragma unroll
  for (int ot = 0; ot < 2; ++ot) {
    float a = ss[ot], b = qq[ot];
    a += __shfl_down(a, 32); a += __shfl_down(a, 16);
    b += __shfl_down(b, 32); b += __shfl_down(b, 16);
    if (kg == 0) {
      atomicAdd(&sum3[ot * 16 + lj], a);
      atomicAdd(&sq3[ot * 16 + lj], b);
    }
  }
}

// ---------------- K7: bn3 + residual + scatter back (4 elems/thread) --------
__global__ __launch_bounds__(256) void k7_out(
    const float* __restrict__ x, const bf16* __restrict__ y3,
    const float* __restrict__ sc3, const float* __restrict__ sh3,
    float* __restrict__ out) {
  int idx = (blockIdx.x * 256 + threadIdx.x) * 4;  // 16*32*128*128 total
  int wcol = idx & 127;
  int hrow = (idx >> 7) & 127;
  int o2 = (idx >> 14) & 31;
  int bi = idx >> 19;
  int g = bi * 64 + (hrow >> 4) * 8 + (wcol >> 4);
  ushort4v u = *(const ushort4v*)((const unsigned short*)y3 +
                                  ((size_t)g * 32 + o2) * SP2 +
                                  ((hrow & 15) << 4) + (wcol & 15));
  float4 xv = *(const float4*)(x + idx);
  float sc = sc3[o2], sh = sh3[o2];
  float4 ov;
  ov.x = xv.x + b2f(u.x) * sc + sh;
  ov.y = xv.y + b2f(u.y) * sc + sh;
  ov.z = xv.z + b2f(u.z) * sc + sh;
  ov.w = xv.w + b2f(u.w) * sc + sh;
  *(float4*)(out + idx) = ov;
}

extern "C" void kernel_launch(void* const* d_in, const int* in_sizes, int n_in,
                              void* d_out, int out_size, void* d_ws, size_t ws_size,
                              hipStream_t stream) {
  const float* x  = (const float*)d_in[0];
  const float* s  = (const float*)d_in[1];
  const float* g1 = (const float*)d_in[2];
  const float* b1 = (const float*)d_in[3];
  const float* g2 = (const float*)d_in[4];
  const float* b2 = (const float*)d_in[5];
  const float* g3 = (const float*)d_in[6];
  const float* b3 = (const float*)d_in[7];
  float* out = (float*)d_out;

  char* ws = (char*)d_ws;
  float* stats = (float*)ws;
  float* sum1 = stats;        float* sq1 = stats + 192;
  float* sum2 = stats + 384;  float* sq2 = stats + 576;
  float* sum3 = stats + 768;  float* sq3 = stats + 800;
  float* sc1 = stats + 1024;  float* sh1 = stats + 1216;
  float* sc2 = stats + 1408;  float* sh2 = stats + 1600;
  float* sc3 = stats + 1792;  float* sh3 = stats + 1824;
  bf16* y1 = (bf16*)(ws + 8192);                       // 1024*192*324 bf16
  bf16* y2 = y1 + (size_t)NGRP * HID * SP1;            // 1024*192*256 bf16
  bf16* y3 = y1;                                       // alias: y1 dead by K5
  unsigned short* wt = (unsigned short*)(y2 + (size_t)NGRP * HID * SP2);  // [g][HPAR] bf16

  hipMemsetAsync(stats, 0, 832 * sizeof(float), stream);

  k0_wt<<<16 * 219, 256, 0, stream>>>(s, wt);
  k1_stage1<<<NGRP, 256, 0, stream>>>(x, wt, y1, sum1, sq1);
  k_bnp<<<1, 192, 0, stream>>>(sum1, sq1, g1, b1, sc1, sh1, HID, 1.f / (NGRP * (float)SP1));
  k3_dw<<<NGRP, 256, 0, stream>>>(y1, wt, sc1, sh1, y2, sum2, sq2);
  k_bnp<<<1, 192, 0, stream>>>(sum2, sq2, g2, b2, sc2, sh2, HID, 1.f / (NGRP * (float)SP2));
  k5_stage3<<<NGRP, 256, 0, stream>>>(y2, wt, sc2, sh2, y3, sum3, sq3);
  k_bnp<<<1, 32, 0, stream>>>(sum3, sq3, g3, b3, sc3, sh3, 32, 1.f / (NGRP * (float)SP2));
  k7_out<<<8192, 256, 0, stream>>>(x, y3, sc3, sh3, out);
}

// Round 11
// 224.830 us; speedup vs baseline: 1.3364x; 1.3364x over previous
//
#include <hip/hip_runtime.h>
#include <hip/hip_bf16.h>

// HyperPatchInvertedResidual: per-patch hyper-conv pipeline with global BNs.
// b=16, c=32, H=W=128, 8x8 patches of 16x16 (+1 halo -> 18x18), HID=192.
// G = 16*64 = 1024 groups.

#define HID 192
#define SP1 324   // 18*18
#define SP2 256   // 16*16
#define HPAR 14016
#define R1 6144   // 32*192
#define R2 7872   // R1 + 192*9
#define NGRP 1024
#define PSTR 36   // patch LDS row stride (halves): conflict-free frag reads

typedef __hip_bfloat16 bf16;
typedef __attribute__((ext_vector_type(4))) unsigned short ushort4v;
typedef __attribute__((ext_vector_type(2))) unsigned short ushort2v;  // 4B
typedef __attribute__((ext_vector_type(4))) short short4v;
typedef __attribute__((ext_vector_type(8))) short short8v;
typedef __attribute__((ext_vector_type(4))) float f32x4;
union Frag { short4v h[2]; short8v v; };

__device__ __forceinline__ float b2f(unsigned short u) {
  __hip_bfloat16_raw r; r.x = u;
  return __bfloat162float((bf16)r);
}
__device__ __forceinline__ unsigned short f2b(float f) {
  union { bf16 b; unsigned short u; } c;
  c.b = __float2bfloat16(f);
  return c.u;
}
// XCD-affinity remap: all 64 groups of one batch bi land on XCD bi%8.
__device__ __forceinline__ int remap_g(int blk) {
  int x = blk & 7, q = blk >> 3;
  return (((q >> 6) << 3) + x) * 64 + (q & 63);
}

// ---------------- K0: hyper-weight gather/transpose -------------------------
// s[bi][hp][8][8] f32 (stride-64 per-group gather) -> wt[g][hp] bf16, dense.
__global__ __launch_bounds__(256) void k0_wt(
    const float* __restrict__ s, unsigned short* __restrict__ wt) {
  int blk = blockIdx.x;             // 16 bi x 219 chunks of 64 hp
  int bi = blk / 219, ck = blk - bi * 219;
  int hp0 = ck * 64;
  __shared__ float t[64][65];
  int tid = threadIdx.x;
  int lw = tid >> 6, l = tid & 63;
  const float* sp = s + ((size_t)bi * HPAR + hp0) * 64;
#pragma unroll
  for (int i = 0; i < 16; ++i) {
    int row = lw * 16 + i;
    t[row][l] = sp[(size_t)row * 64 + l];
  }
  __syncthreads();
  int g = lw * 16 + (l >> 2), seg = l & 3;    // 64 g x 4 segs of 16 hp
  unsigned short* wp = wt + ((size_t)(bi * 64 + g)) * HPAR + hp0 + seg * 16;
#pragma unroll
  for (int q = 0; q < 4; ++q) {
    ushort4v ov;
    ov.x = f2b(t[seg * 16 + q * 4 + 0][g]);
    ov.y = f2b(t[seg * 16 + q * 4 + 1][g]);
    ov.z = f2b(t[seg * 16 + q * 4 + 2][g]);
    ov.w = f2b(t[seg * 16 + q * 4 + 3][g]);
    *(ushort4v*)(wp + q * 4) = ov;
  }
}

// ---------------- K1: stage1 1x1 conv 32->192 via MFMA + partial stats ------
// y1[192,324] = w1[192,32] @ patch[32,324] per group. Per-block channel
// partials written as plain stores (no global atomics).
__global__ __launch_bounds__(256) void k1_stage1(
    const float* __restrict__ x, const unsigned short* __restrict__ wt,
    bf16* __restrict__ y1, float* __restrict__ p1s, float* __restrict__ p1q) {
  int g = remap_g(blockIdx.x);
  int bi = g >> 6, fi = (g >> 3) & 7, fj = g & 7;
  __shared__ unsigned short plds[336 * PSTR];    // [sp=336][ci], stride 36
  __shared__ float smS[192], smQ[192];
  int tid = threadIdx.x;
  int w = tid >> 6, l = tid & 63;
  int lj = l & 15, kg = l >> 4;
  const unsigned short* w1g = wt + (size_t)g * HPAR;
  Frag wf[12];
#pragma unroll
  for (int ot = 0; ot < 12; ++ot) {
    const unsigned short* wp = w1g + (ot * 16 + lj) * 32 + 4 * kg;
    wf[ot].h[0] = *(const short4v*)wp;
    wf[ot].h[1] = *(const short4v*)(wp + 16);
  }
  const float* xb = x + (size_t)bi * 32 * 128 * 128;
  for (int idx = tid; idx < 32 * SP1; idx += 256) {
    int ci = idx / SP1, sp = idx - ci * SP1;
    int a = sp / 18, b = sp - a * 18;
    int r = fi * 16 + a - 1; r = r < 0 ? -r : (r > 127 ? 254 - r : r);
    int c = fj * 16 + b - 1; c = c < 0 ? -c : (c > 127 ? 254 - c : c);
    plds[sp * PSTR + ci] = f2b(xb[((size_t)ci * 128 + r) * 128 + c]);
  }
  for (int i = tid; i < 12 * PSTR; i += 256) plds[SP1 * PSTR + i] = 0;  // pad rows
  if (tid < 192) { smS[tid] = 0.f; smQ[tid] = 0.f; }
  __syncthreads();

  float sreg[12], qreg[12];
#pragma unroll
  for (int ot = 0; ot < 12; ++ot) { sreg[ot] = 0.f; qreg[ot] = 0.f; }
  unsigned short* yg = (unsigned short*)y1 + (size_t)g * HID * SP1;
#pragma unroll 1
  for (int sti = 0; sti < 6; ++sti) {
    int st = sti * 4 + w;          // interleaved: balances the 21-tile tail
    int sp0 = st * 16;
    if (sp0 >= SP1) continue;      // tiles 21..23 are pure pad
    const unsigned short* pb = plds + (sp0 + lj) * PSTR + 4 * kg;
    Frag tf;
    tf.h[0] = *(const short4v*)pb;
    tf.h[1] = *(const short4v*)(pb + 16);
    int spb = sp0 + kg * 4;
    bool stok = spb + 3 < SP1;     // tile 20: only kg=0 (sp 320..323) valid
#pragma unroll
    for (int ot = 0; ot < 12; ++ot) {
      f32x4 zz = {0.f, 0.f, 0.f, 0.f};
      f32x4 d = __builtin_amdgcn_mfma_f32_16x16x32_bf16(tf.v, wf[ot].v, zz, 0, 0, 0);
      if (stok) {
        sreg[ot] += d[0] + d[1] + d[2] + d[3];
        qreg[ot] += d[0] * d[0] + d[1] * d[1] + d[2] * d[2] + d[3] * d[3];
        short4v ov;
        ov.x = (short)f2b(d[0]); ov.y = (short)f2b(d[1]);
        ov.z = (short)f2b(d[2]); ov.w = (short)f2b(d[3]);
        *(short4v*)(yg + (size_t)(ot * 16 + lj) * SP1 + spb) = ov;
      }
    }
  }
  // stats tail: kg-lane reduce, LDS combine, per-block partial stores
#pragma unroll
  for (int ot = 0; ot < 12; ++ot) {
    float a = sreg[ot], b = qreg[ot];
    a += __shfl_down(a, 32); a += __shfl_down(a, 16);
    b += __shfl_down(b, 32); b += __shfl_down(b, 16);
    if (kg == 0) {
      atomicAdd(&smS[ot * 16 + lj], a);
      atomicAdd(&smQ[ot * 16 + lj], b);
    }
  }
  __syncthreads();
  if (tid < 192) {
    p1s[(size_t)blockIdx.x * 192 + tid] = smS[tid];
    p1q[(size_t)blockIdx.x * 192 + tid] = smQ[tid];
  }
}

// ---------------- bn reduce + params: partials -> scale/shift ---------------
__global__ __launch_bounds__(256) void k_bnp_red(
    const float* __restrict__ ps, const float* __restrict__ pq,
    const float* __restrict__ gamma, const float* __restrict__ beta,
    float* __restrict__ sc, float* __restrict__ sh,
    int CH, int NP, float invN) {
  int ch = blockIdx.x;
  int tid = threadIdx.x;
  float s = 0.f, q = 0.f;
  for (int i = tid; i < NP; i += 256) {
    s += ps[(size_t)i * CH + ch];
    q += pq[(size_t)i * CH + ch];
  }
#pragma unroll
  for (int off = 32; off; off >>= 1) {
    s += __shfl_down(s, off);
    q += __shfl_down(q, off);
  }
  __shared__ float red[8];
  int lane = tid & 63, wv = tid >> 6;
  if (lane == 0) { red[wv] = s; red[4 + wv] = q; }
  __syncthreads();
  if (tid == 0) {
    float S = red[0] + red[1] + red[2] + red[3];
    float Q = red[4] + red[5] + red[6] + red[7];
    float m = S * invN;
    float v = Q * invN - m * m;
    float scale = gamma[ch] * rsqrtf(v + 1e-5f);
    sc[ch] = scale;
    sh[ch] = beta[ch] - m * scale;
  }
}

// ---------------- K3: bn1+relu6 then 3x3 depthwise + partial stats ----------
// LDS-free: thread-task = (channel, 4-col quad, all 16 out rows). Quad lanes
// are consecutive -> shfl(1/2) reduce, leader plain-stores its partial.
__global__ __launch_bounds__(256) void k3_dw(
    const bf16* __restrict__ y1, const unsigned short* __restrict__ wt,
    const float* __restrict__ sc1, const float* __restrict__ sh1,
    bf16* __restrict__ y2, float* __restrict__ p2s, float* __restrict__ p2q) {
  int g = remap_g(blockIdx.x);
  const unsigned short* w2g = wt + (size_t)g * HPAR + R1;
  const unsigned short* y1g = (const unsigned short*)y1 + (size_t)g * HID * SP1;
  unsigned short* y2g = (unsigned short*)y2 + (size_t)g * HID * SP2;
  int tid = threadIdx.x;
#pragma unroll 1
  for (int p = 0; p < 3; ++p) {
    int tau = tid + 256 * p;            // 0..767
    int ch = tau >> 2, c4 = (tau & 3) * 4;
    float scv = sc1[ch], shv = sh1[ch];
    float wk[9];
#pragma unroll
    for (int k = 0; k < 9; ++k) wk[k] = b2f(w2g[ch * 9 + k]);
    const unsigned short* rp = y1g + ch * SP1 + c4;
    unsigned short* op = y2g + ch * SP2 + c4;
    float accR[3][4];
    float s0 = 0.f, s1 = 0.f;
#pragma unroll
    for (int ir = 0; ir < 18; ++ir) {
      ushort2v q0 = *(const ushort2v*)(rp + ir * 18);
      ushort2v q1 = *(const ushort2v*)(rp + ir * 18 + 2);
      ushort2v q2 = *(const ushort2v*)(rp + ir * 18 + 4);
      float w6[6];
      w6[0] = fminf(fmaxf(b2f(q0.x) * scv + shv, 0.f), 6.f);
      w6[1] = fminf(fmaxf(b2f(q0.y) * scv + shv, 0.f), 6.f);
      w6[2] = fminf(fmaxf(b2f(q1.x) * scv + shv, 0.f), 6.f);
      w6[3] = fminf(fmaxf(b2f(q1.y) * scv + shv, 0.f), 6.f);
      w6[4] = fminf(fmaxf(b2f(q2.x) * scv + shv, 0.f), 6.f);
      w6[5] = fminf(fmaxf(b2f(q2.y) * scv + shv, 0.f), 6.f);
#pragma unroll
      for (int k = 0; k < 3; ++k) {     // in row ir feeds out row ir-k (tap k)
        int orow = ir - k;
        if (orow < 0 || orow >= 16) continue;
        float* A = accR[orow % 3];      // static under full unroll
#pragma unroll
        for (int j = 0; j < 4; ++j) {
          float t = w6[j] * wk[3 * k] + w6[j + 1] * wk[3 * k + 1] +
                    w6[j + 2] * wk[3 * k + 2];
          A[j] = (k == 0) ? t : A[j] + t;
        }
        if (k == 2) {
          s0 += A[0] + A[1] + A[2] + A[3];
          s1 += A[0] * A[0] + A[1] * A[1] + A[2] * A[2] + A[3] * A[3];
          ushort4v ov;
          ov.x = f2b(A[0]); ov.y = f2b(A[1]);
          ov.z = f2b(A[2]); ov.w = f2b(A[3]);
          *(ushort4v*)(op + orow * 16) = ov;
        }
      }
    }
    // quad reduce (lanes 4q..4q+3 share ch), leader stores partial
    s0 += __shfl_down(s0, 1); s0 += __shfl_down(s0, 2);
    s1 += __shfl_down(s1, 1); s1 += __shfl_down(s1, 2);
    if ((tid & 3) == 0) {
      p2s[(size_t)blockIdx.x * 192 + ch] = s0;
      p2q[(size_t)blockIdx.x * 192 + ch] = s1;
    }
  }
}

// ---------------- K5: bn2+relu6 then 1x1 conv 192->32 via MFMA + partials ---
__global__ __launch_bounds__(256) void k5_stage3(
    const bf16* __restrict__ y2, const unsigned short* __restrict__ wt,
    const float* __restrict__ sc2, const float* __restrict__ sh2,
    bf16* __restrict__ y3, float* __restrict__ p3s, float* __restrict__ p3q) {
  int g = remap_g(blockIdx.x);
  const unsigned short* w3g = wt + (size_t)g * HPAR + R2;   // [o2][k=192]
  __shared__ unsigned short bt[256 * PSTR];      // [sp=256][k-chunk=32], stride 36
  int tid = threadIdx.x;
  int w = tid >> 6, l = tid & 63;
  int lj = l & 15, kg = l >> 4;
  f32x4 acc[4][2] = {};
  const unsigned short* y2g = (const unsigned short*)y2 + (size_t)g * HID * SP2;
#pragma unroll 1
  for (int kc = 0; kc < 6; ++kc) {
    if (kc) __syncthreads();   // protect bt from previous chunk's readers
#pragma unroll
    for (int uu = 0; uu < 2; ++uu) {
      int u = tid + 256 * uu;
      int tq = u & 7, spq = u >> 3;           // k-quad, sp-quad
      int o0 = kc * 32 + tq * 4;
      float4 scv = *(const float4*)(sc2 + o0);
      float4 shv = *(const float4*)(sh2 + o0);
      unsigned short hbuf[4][4];
#pragma unroll
      for (int e = 0; e < 4; ++e) {
        ushort4v v = *(const ushort4v*)(y2g + (size_t)(o0 + e) * SP2 + spq * 4);
        float sce = ((const float*)&scv)[e], she = ((const float*)&shv)[e];
#pragma unroll
        for (int j = 0; j < 4; ++j) {
          float f = b2f(((const unsigned short*)&v)[j]) * sce + she;
          hbuf[e][j] = f2b(fminf(fmaxf(f, 0.f), 6.f));
        }
      }
#pragma unroll
      for (int j = 0; j < 4; ++j) {
        ushort4v wv;
        wv.x = hbuf[0][j]; wv.y = hbuf[1][j]; wv.z = hbuf[2][j]; wv.w = hbuf[3][j];
        *(ushort4v*)(bt + (spq * 4 + j) * PSTR + tq * 4) = wv;
      }
    }
    __syncthreads();
    Frag wf[2];
#pragma unroll
    for (int ot = 0; ot < 2; ++ot) {
      const unsigned short* wp = w3g + (ot * 16 + lj) * HID + kc * 32 + 4 * kg;
      wf[ot].h[0] = *(const short4v*)wp;
      wf[ot].h[1] = *(const short4v*)(wp + 16);
    }
#pragma unroll
    for (int sti = 0; sti < 4; ++sti) {
      const unsigned short* pb = bt + ((w + 4 * sti) * 16 + lj) * PSTR + 4 * kg;
      Frag tf;
      tf.h[0] = *(const short4v*)pb;
      tf.h[1] = *(const short4v*)(pb + 16);
#pragma unroll
      for (int ot = 0; ot < 2; ++ot)
        acc[sti][ot] = __builtin_amdgcn_mfma_f32_16x16x32_bf16(
            tf.v, wf[ot].v, acc[sti][ot], 0, 0, 0);
    }
  }
  // D[m=kg*4+r][n=lj]: m -> sp, n -> o2: direct short4 stores + stats.
  unsigned short* yg3 = (unsigned short*)y3 + (size_t)g * 32 * SP2;
  float ss[2] = {0.f, 0.f}, qq[2] = {0.f, 0.f};
#pragma unroll
  for (int sti = 0; sti < 4; ++sti) {
    int spb = (w + 4 * sti) * 16 + kg * 4;
#pragma unroll
    for (int ot = 0; ot < 2; ++ot) {
      int o2 = ot * 16 + lj;
      f32x4 d = acc[sti][ot];
      ss[ot] += d[0] + d[1] + d[2] + d[3];
      qq[ot] += d[0] * d[0] + d[1] * d[1] + d[2] * d[2] + d[3] * d[3];
      short4v ov;
      ov.x = (short)f2b(d[0]); ov.y = (short)f2b(d[1]);
      ov.z = (short)f2b(d[2]); ov.w = (short)f2b(d[3]);
      *(short4v*)(yg3 + (size_t)o2 * SP2 + spb) = ov;
    }
  }
  // per-wave partial stores (kg==0 lanes hold the wave's channel sums)
#pragma unroll
  for (int ot = 0; ot < 2; ++ot) {
    float a = ss[ot], b = qq[ot];
    a += __shfl_down(a, 32); a += __shfl_down(a, 16);
    b += __shfl_down(b, 32); b += __shfl_down(b, 16);
    if (kg == 0) {
      size_t base = ((size_t)blockIdx.x * 4 + w) * 32 + ot * 16 + l;
      p3s[base] = a;
      p3q[base] = b;
    }
  }
}

// ---------------- K7: bn3 + residual + scatter back (4 elems/thread) --------
__global__ __launch_bounds__(256) void k7_out(
    const float* __restrict__ x, const bf16* __restrict__ y3,
    const float* __restrict__ sc3, const float* __restrict__ sh3,
    float* __restrict__ out) {
  int idx = (blockIdx.x * 256 + threadIdx.x) * 4;  // 16*32*128*128 total
  int wcol = idx & 127;
  int hrow = (idx >> 7) & 127;
  int o2 = (idx >> 14) & 31;
  int bi = idx >> 19;
  int g = bi * 64 + (hrow >> 4) * 8 + (wcol >> 4);
  ushort4v u = *(const ushort4v*)((const unsigned short*)y3 +
                                  ((size_t)g * 32 + o2) * SP2 +
                                  ((hrow & 15) << 4) + (wcol & 15));
  float4 xv = *(const float4*)(x + idx);
  float sc = sc3[o2], sh = sh3[o2];
  float4 ov;
  ov.x = xv.x + b2f(u.x) * sc + sh;
  ov.y = xv.y + b2f(u.y) * sc + sh;
  ov.z = xv.z + b2f(u.z) * sc + sh;
  ov.w = xv.w + b2f(u.w) * sc + sh;
  *(float4*)(out + idx) = ov;
}

extern "C" void kernel_launch(void* const* d_in, const int* in_sizes, int n_in,
                              void* d_out, int out_size, void* d_ws, size_t ws_size,
                              hipStream_t stream) {
  const float* x  = (const float*)d_in[0];
  const float* s  = (const float*)d_in[1];
  const float* g1 = (const float*)d_in[2];
  const float* b1 = (const float*)d_in[3];
  const float* g2 = (const float*)d_in[4];
  const float* b2 = (const float*)d_in[5];
  const float* g3 = (const float*)d_in[6];
  const float* b3 = (const float*)d_in[7];
  float* out = (float*)d_out;

  char* ws = (char*)d_ws;
  float* stats = (float*)ws;        // sc/sh only (no accumulators anymore)
  float* sc1 = stats;         float* sh1 = stats + 192;
  float* sc2 = stats + 384;   float* sh2 = stats + 576;
  float* sc3 = stats + 768;   float* sh3 = stats + 800;
  bf16* y1 = (bf16*)(ws + 8192);                       // 1024*192*324 bf16
  bf16* y2 = y1 + (size_t)NGRP * HID * SP1;            // 1024*192*256 bf16
  bf16* y3 = y1;                                       // alias: y1 dead by K5
  unsigned short* wt = (unsigned short*)(y2 + (size_t)NGRP * HID * SP2);  // [g][HPAR] bf16

  // Partial-sum scratch, zero workspace growth:
  //  p1 aliases the y2 region (y2 is written only AFTER p1 is consumed);
  //  p2/p3 alias d_out (k7 fully overwrites d_out at the end).
  float* p1s = (float*)y2;            float* p1q = p1s + 192 * 1024;
  float* p2s = (float*)d_out;         float* p2q = p2s + 192 * 1024;
  float* p3s = p2q + 192 * 1024;      float* p3q = p3s + 32 * 4096;

  k0_wt<<<16 * 219, 256, 0, stream>>>(s, wt);
  k1_stage1<<<NGRP, 256, 0, stream>>>(x, wt, y1, p1s, p1q);
  k_bnp_red<<<192, 256, 0, stream>>>(p1s, p1q, g1, b1, sc1, sh1,
                                     HID, NGRP, 1.f / (NGRP * (float)SP1));
  k3_dw<<<NGRP, 256, 0, stream>>>(y1, wt, sc1, sh1, y2, p2s, p2q);
  k_bnp_red<<<192, 256, 0, stream>>>(p2s, p2q, g2, b2, sc2, sh2,
                                     HID, NGRP, 1.f / (NGRP * (float)SP2));
  k5_stage3<<<NGRP, 256, 0, stream>>>(y2, wt, sc2, sh2, y3, p3s, p3q);
  k_bnp_red<<<32, 256, 0, stream>>>(p3s, p3q, g3, b3, sc3, sh3,
                                    32, NGRP * 4, 1.f / (NGRP * (float)SP2));
  k7_out<<<8192, 256, 0, stream>>>(x, y3, sc3, sh3, out);
}